// Round 2
// baseline (13677.260 us; speedup 1.0000x reference)
//
#include <hip/hip_runtime.h>
#include <cstdint>
#include <cstddef>

#define B_ 64
#define S_ 512
#define H_ 1024
#define E_ 128
#define L_ 49
#define G3_ 3072   // 3*H
#define K_ 1152    // E+H
#define C_ 64      // chunk length (steps) -- even, so h state round-trips to hA
#define NCH_ 8     // 512 / C_

// ---------------------------------------------------------------------------
// init: zero h buffers + barrier state (hA,hB,bar contiguous = 132096 dwords)
// ---------------------------------------------------------------------------
__global__ __launch_bounds__(256) void init_kernel(float4* __restrict__ p)
{
  const int i = blockIdx.x * 256 + threadIdx.x;   // grid 129*256 = 33024 exact
  p[i] = make_float4(0.f, 0.f, 0.f, 0.f);
}

// ---------------------------------------------------------------------------
// Phase 1 (per chunk): gxC[tl][c][b] = sum_i x[b,t0+tl,i]*w_ih[c,i] + b_ih[c]
//   x = concat(emb_table[prev_id[b,t]] (128), word_emb[b,t] (1024))
//   Output layout TRANSPOSED: [t_local][c][b], b contiguous for the scan.
// ---------------------------------------------------------------------------
__global__ __launch_bounds__(256) void gx_gemm(
    const float* __restrict__ word, const int* __restrict__ labels,
    const float* __restrict__ emb, const float* __restrict__ w_ih,
    const float* __restrict__ b_ih, float* __restrict__ gxC, int t0)
{
  __shared__ float xs[2][32][72];    // [k][b], padded
  __shared__ float wsm[2][32][136];  // [k][c], padded

  const int bid = blockIdx.x;
  const int Tl = bid / 24;           // 0..C_-1
  const int T  = t0 + Tl;            // global t
  const int cb = bid % 24;
  const int tid = threadIdx.x;

  const int xb = tid >> 2, xkq = tid & 3;           // x: 8 k's per thread
  const int pid = (T > 0) ? labels[xb * S_ + T - 1] : 0;
  const float* xsrcA = emb + (size_t)pid * E_;                   // k in [0,128)
  const float* xsrcB = word + ((size_t)xb * S_ + T) * H_ - E_;   // k in [128,1152)
  const int wc = tid >> 1, wkh = tid & 1;           // w: 16 k's per thread
  const float* wrow = w_ih + (size_t)(cb * 128 + wc) * K_;

  float4 xr0, xr1, wr0, wr1, wr2, wr3;

  auto load_tile = [&](int kt) {
    const int kg = kt * 32;
    const float* xsrc = (kg < E_) ? (xsrcA + kg) : (xsrcB + kg);
    xr0 = *(const float4*)(xsrc + xkq * 8);
    xr1 = *(const float4*)(xsrc + xkq * 8 + 4);
    const float* wsrc = wrow + kg + wkh * 16;
    wr0 = *(const float4*)(wsrc);
    wr1 = *(const float4*)(wsrc + 4);
    wr2 = *(const float4*)(wsrc + 8);
    wr3 = *(const float4*)(wsrc + 12);
  };
  auto store_tile = [&](int bf) {
#pragma unroll
    for (int i = 0; i < 4; ++i) xs[bf][xkq * 8 + i][xb]     = ((const float*)&xr0)[i];
#pragma unroll
    for (int i = 0; i < 4; ++i) xs[bf][xkq * 8 + 4 + i][xb] = ((const float*)&xr1)[i];
#pragma unroll
    for (int i = 0; i < 4; ++i) wsm[bf][wkh * 16 + i][wc]      = ((const float*)&wr0)[i];
#pragma unroll
    for (int i = 0; i < 4; ++i) wsm[bf][wkh * 16 + 4 + i][wc]  = ((const float*)&wr1)[i];
#pragma unroll
    for (int i = 0; i < 4; ++i) wsm[bf][wkh * 16 + 8 + i][wc]  = ((const float*)&wr2)[i];
#pragma unroll
    for (int i = 0; i < 4; ++i) wsm[bf][wkh * 16 + 12 + i][wc] = ((const float*)&wr3)[i];
  };

  const int cg = tid >> 4, bg = tid & 15;   // thread: 8 c's x 4 b's
  float acc[8][4];
#pragma unroll
  for (int i = 0; i < 8; ++i)
#pragma unroll
    for (int j = 0; j < 4; ++j) acc[i][j] = 0.f;

  load_tile(0);
  store_tile(0);
  __syncthreads();

  for (int kt = 0; kt < 36; ++kt) {
    const int cur = kt & 1;
    if (kt < 35) load_tile(kt + 1);   // global prefetch overlaps compute
#pragma unroll 4
    for (int k = 0; k < 32; ++k) {
      const float4 xv  = *(const float4*)&xs[cur][k][bg * 4];
      const float4 wv0 = *(const float4*)&wsm[cur][k][cg * 8];
      const float4 wv1 = *(const float4*)&wsm[cur][k][cg * 8 + 4];
      const float wv[8] = {wv0.x, wv0.y, wv0.z, wv0.w, wv1.x, wv1.y, wv1.z, wv1.w};
      const float xa[4] = {xv.x, xv.y, xv.z, xv.w};
#pragma unroll
      for (int ci = 0; ci < 8; ++ci)
#pragma unroll
        for (int bi = 0; bi < 4; ++bi)
          acc[ci][bi] = fmaf(wv[ci], xa[bi], acc[ci][bi]);
    }
    if (kt < 35) store_tile(cur ^ 1);
    __syncthreads();
  }

  const size_t obase = ((size_t)Tl * G3_ + (size_t)cb * 128) * 64;
#pragma unroll
  for (int ci = 0; ci < 8; ++ci) {
    const int c = cg * 8 + ci;
    const float bv = b_ih[cb * 128 + c];
    float4 o;
    o.x = acc[ci][0] + bv; o.y = acc[ci][1] + bv;
    o.z = acc[ci][2] + bv; o.w = acc[ci][3] + bv;
    *(float4*)&gxC[obase + (size_t)c * 64 + bg * 4] = o;
  }
}

// ---------------------------------------------------------------------------
// Two-level grid barrier (16 groups x 16 WGs), agent-scope atomics.
// Safe: grid=256 at 1 WG/CU (LDS>80KB) on 256 CUs -> all co-resident.
// Generation counter `gen` is monotone across chunk launches (targets passed in).
// ---------------------------------------------------------------------------
__device__ __forceinline__ void grid_barrier(unsigned* bar, unsigned target, int wg)
{
  __syncthreads();
  if (threadIdx.x == 0) {
    unsigned* grp  = bar + (wg & 15) * 32;
    unsigned* root = bar + 512;
    unsigned* gen  = bar + 544;
    const unsigned old =
        __hip_atomic_fetch_add(grp, 1u, __ATOMIC_ACQ_REL, __HIP_MEMORY_SCOPE_AGENT);
    if (old == 15u) {
      const unsigned r =
          __hip_atomic_fetch_add(root, 1u, __ATOMIC_ACQ_REL, __HIP_MEMORY_SCOPE_AGENT);
      if (r == 15u) {
#pragma unroll
        for (int i = 0; i < 16; ++i)
          __hip_atomic_store(bar + i * 32, 0u, __ATOMIC_RELAXED, __HIP_MEMORY_SCOPE_AGENT);
        __hip_atomic_store(root, 0u, __ATOMIC_RELAXED, __HIP_MEMORY_SCOPE_AGENT);
        __hip_atomic_store(gen, target, __ATOMIC_RELEASE, __HIP_MEMORY_SCOPE_AGENT);
      }
    }
    while (__hip_atomic_load(gen, __ATOMIC_RELAXED, __HIP_MEMORY_SCOPE_AGENT) < target)
      __builtin_amdgcn_s_sleep(2);
    (void)__hip_atomic_load(gen, __ATOMIC_ACQUIRE, __HIP_MEMORY_SCOPE_AGENT);
  }
  __syncthreads();
}

// ---------------------------------------------------------------------------
// Phase 2 (per chunk): sequential GRU scan, C_ steps. 256 WGs x 512 thr, 1/CU.
// WG g owns h-cols j in [4g,4g+4) (gate rows j, 1024+j, 2048+j).
// w_hh slice (12x1024, 48KB) in LDS for the whole chunk.
// K split across 8 waves; LDS reduce; grid barrier per step.
// h layout [k][b]; outsC layout [t_local][k][b].
// Invariant: h_in arrives in hA; C_ even => h_out lands in hA.
// ---------------------------------------------------------------------------
__global__ __launch_bounds__(512, 1) void scan_kernel(
    const float* __restrict__ gxC, const float* __restrict__ w_hh,
    const float* __restrict__ b_hh, float* hA, float* hB,
    float* __restrict__ outsC, unsigned* bar, unsigned step0)
{
  __shared__ float wsm[12 * 1024];     // 48KB  [c_local][k]
  __shared__ float red[8][17][64];     // 34.8KB -> total ~84KB -> 1 WG/CU
  const int g = blockIdx.x;
  const int tid = threadIdx.x;
  const int lane = tid & 63;
  const int wave = tid >> 6;

  for (int idx = tid; idx < 3072; idx += 512) {
    const int c = idx >> 8;          // local row 0..11 = gate*4 + jj
    const int k4 = idx & 255;
    const int gate = c >> 2, jj = c & 3;
    *(float4*)&wsm[c * 1024 + (k4 << 2)] =
        *(const float4*)&w_hh[(size_t)(gate * 1024 + g * 4 + jj) * 1024 + (k4 << 2)];
  }

  float bhr = 0.f, bhz = 0.f, bhn = 0.f;
  int j = 0, b = 0;
  if (tid < 256) {
    b = tid & 63;
    const int jj = tid >> 6;
    j = g * 4 + jj;
    bhr = b_hh[j]; bhz = b_hh[1024 + j]; bhn = b_hh[2048 + j];
  }
  __syncthreads();

  float* hcur = hA;
  float* hnxt = hB;
  const int k0 = wave << 7;

  for (int s = 0; s < C_; ++s) {
    float gxr = 0.f, gxz = 0.f, gxn = 0.f, hold = 0.f;
    if (tid < 256) {
      const size_t gb = (size_t)s * G3_ * 64;
      gxr  = gxC[gb + (size_t)j * 64 + b];
      gxz  = gxC[gb + (size_t)(1024 + j) * 64 + b];
      gxn  = gxC[gb + (size_t)(2048 + j) * 64 + b];
      hold = hcur[(j << 6) + b];
    }

    float acc[12];
#pragma unroll
    for (int c = 0; c < 12; ++c) acc[c] = 0.f;
    const float* hq = hcur + (k0 << 6) + lane;
    for (int kk = 0; kk < 128; kk += 4) {
      const float h0 = hq[0];
      const float h1 = hq[64];
      const float h2 = hq[128];
      const float h3 = hq[192];
      hq += 256;
#pragma unroll
      for (int c = 0; c < 12; ++c) {
        const float4 w = *(const float4*)&wsm[c * 1024 + k0 + kk];
        acc[c] = fmaf(w.w, h3, fmaf(w.z, h2, fmaf(w.y, h1, fmaf(w.x, h0, acc[c]))));
      }
    }
#pragma unroll
    for (int c = 0; c < 12; ++c) red[wave][c][lane] = acc[c];
    __syncthreads();

    if (tid < 256) {
      const int jj = tid >> 6;
      float rs = 0.f, zs = 0.f, ns = 0.f;
#pragma unroll
      for (int w = 0; w < 8; ++w) {
        rs += red[w][jj][b];
        zs += red[w][4 + jj][b];
        ns += red[w][8 + jj][b];
      }
      const float r = 1.0f / (1.0f + expf(-(gxr + rs + bhr)));
      const float z = 1.0f / (1.0f + expf(-(gxz + zs + bhz)));
      const float n = tanhf(gxn + r * (ns + bhn));
      const float hnew = (1.0f - z) * n + z * hold;
      __hip_atomic_store(&hnxt[(j << 6) + b], hnew, __ATOMIC_RELAXED, __HIP_MEMORY_SCOPE_AGENT);
      outsC[((size_t)s << 16) + (j << 6) + b] = hnew;
    }
    grid_barrier(bar, step0 + (unsigned)s + 1u, g);
    float* t_ = hcur; hcur = hnxt; hnxt = t_;
  }
}

// ---------------------------------------------------------------------------
// Phase 3 (per chunk): logits[b,t,l] = outsC[tl,:,b].w_out[l,:] + b_out[l],
// IOBES-masked from prev label. One WG per t_local.
// ---------------------------------------------------------------------------
__global__ __launch_bounds__(256) void logits_kernel(
    const float* __restrict__ outsC, const int* __restrict__ labels,
    const float* __restrict__ w_out, const float* __restrict__ b_out,
    float* __restrict__ out, int t0)
{
  __shared__ float hs[128 * 64];
  __shared__ float wso[49 * 128];
  const int tl = blockIdx.x;
  const int t  = t0 + tl;
  const int tid = threadIdx.x;
  const int b = tid & 63, lq = tid >> 6;
  const int l0 = lq * 13;
  const int nl = (lq == 3) ? 10 : 13;

  float acc[13];
#pragma unroll
  for (int i = 0; i < 13; ++i) acc[i] = 0.f;

  for (int kc = 0; kc < 8; ++kc) {
    __syncthreads();
#pragma unroll
    for (int i = 0; i < 8; ++i) {
      const int flat = (i << 10) + (tid << 2);
      *(float4*)&hs[flat] = *(const float4*)&outsC[((size_t)tl << 16) + (kc << 13) + flat];
    }
    for (int idx = tid; idx < 1568; idx += 256) {
      const int l = idx >> 5, k4 = idx & 31;
      *(float4*)&wso[l * 128 + (k4 << 2)] =
          *(const float4*)&w_out[(size_t)l * 1024 + (kc << 7) + (k4 << 2)];
    }
    __syncthreads();
    for (int k = 0; k < 128; k += 4) {
      const float h0 = hs[((k + 0) << 6) + b];
      const float h1 = hs[((k + 1) << 6) + b];
      const float h2 = hs[((k + 2) << 6) + b];
      const float h3 = hs[((k + 3) << 6) + b];
#pragma unroll
      for (int li = 0; li < 13; ++li) {
        if (li < nl) {
          const float4 w = *(const float4*)&wso[(l0 + li) * 128 + k];
          acc[li] = fmaf(w.w, h3, fmaf(w.z, h2, fmaf(w.y, h1, fmaf(w.x, h0, acc[li]))));
        }
      }
    }
  }

  const int pid = (t > 0) ? labels[b * S_ + t - 1] : 0;
  bool prevOES;
  int ptype = 0;
  if (pid == 0) { prevOES = true; }
  else {
    const int pp = (pid - 1) & 3;   // 0:B 1:I 2:E 3:S
    prevOES = (pp >= 2);
    ptype = (pid - 1) >> 2;
  }
#pragma unroll
  for (int li = 0; li < 13; ++li) {
    if (li < nl) {
      const int l = l0 + li;
      bool ok;
      if (prevOES) {
        ok = (l == 0) || (((l - 1) & 3) == 0) || (((l - 1) & 3) == 3);  // O, B-*, S-*
      } else {
        ok = (l > 0) && (((l - 1) >> 2) == ptype) &&
             ((((l - 1) & 3) == 1) || (((l - 1) & 3) == 2));            // I-T, E-T
      }
      out[(((size_t)b << 9) + t) * 49 + l] = ok ? (acc[li] + b_out[l]) : -1e12f;
    }
  }
}

// ---------------------------------------------------------------------------
// ws layout (total 64.5 MB):
//   gxC   @ 0          : 50,331,648 B   [C_][3072][64] f32
//   outsC @ 50,331,648 : 16,777,216 B   [C_][1024][64] f32
//   hA    @ 67,108,864 :    262,144 B
//   hB    @ 67,371,008 :    262,144 B
//   bar   @ 67,633,152 :      4,096 B   (hA..bar contiguous -> one init kernel)
// ---------------------------------------------------------------------------
extern "C" void kernel_launch(void* const* d_in, const int* in_sizes, int n_in,
                              void* d_out, int out_size, void* d_ws, size_t ws_size,
                              hipStream_t stream)
{
  const float* word   = (const float*)d_in[0];
  const int*   labels = (const int*)d_in[1];
  const float* emb    = (const float*)d_in[2];
  const float* w_ih   = (const float*)d_in[3];
  const float* w_hh   = (const float*)d_in[4];
  const float* b_hh   = (const float*)d_in[6];
  const float* b_ih   = (const float*)d_in[5];
  const float* w_out  = (const float*)d_in[7];
  const float* b_out  = (const float*)d_in[8];
  float* out = (float*)d_out;

  char* ws = (char*)d_ws;
  float*    gxC   = (float*)ws;
  float*    outsC = (float*)(ws + 50331648ull);
  float*    hA    = (float*)(ws + 67108864ull);
  float*    hB    = (float*)(ws + 67371008ull);
  unsigned* bar   = (unsigned*)(ws + 67633152ull);

  init_kernel<<<dim3(129), dim3(256), 0, stream>>>((float4*)hA);  // hA,hB,bar = 0

  for (int ch = 0; ch < NCH_; ++ch) {
    const int t0 = ch * C_;
    gx_gemm<<<dim3(C_ * 24), dim3(256), 0, stream>>>(word, labels, emb, w_ih, b_ih,
                                                     gxC, t0);
    scan_kernel<<<dim3(256), dim3(512), 0, stream>>>(gxC, w_hh, b_hh, hA, hB,
                                                     outsC, bar, (unsigned)t0);
    logits_kernel<<<dim3(C_), dim3(256), 0, stream>>>(outsC, labels, w_out, b_out,
                                                      out, t0);
  }
}

// Round 3
// 13081.793 us; speedup vs baseline: 1.0455x; 1.0455x over previous
//
#include <hip/hip_runtime.h>
#include <cstdint>
#include <cstddef>

#define B_ 64
#define S_ 512
#define H_ 1024
#define E_ 128
#define L_ 49
#define G3_ 3072   // 3*H
#define K_ 1152    // E+H
#define C_ 64      // chunk length (steps) -- even, so h state round-trips to hA
#define NCH_ 8     // 512 / C_

// ---------------------------------------------------------------------------
// init: zero h buffers + barrier state (hA,hB,bar contiguous = 132096 dwords)
// ---------------------------------------------------------------------------
__global__ __launch_bounds__(256) void init_kernel(float4* __restrict__ p)
{
  const int i = blockIdx.x * 256 + threadIdx.x;   // grid 129*256 = 33024 exact
  p[i] = make_float4(0.f, 0.f, 0.f, 0.f);
}

// ---------------------------------------------------------------------------
// Phase 1 (per chunk): gxC[tl][c][b] = sum_i x[b,t0+tl,i]*w_ih[c,i] + b_ih[c]
//   x = concat(emb_table[prev_id[b,t]] (128), word_emb[b,t] (1024))
//   Output layout TRANSPOSED: [t_local][c][b], b contiguous for the scan.
// ---------------------------------------------------------------------------
__global__ __launch_bounds__(256) void gx_gemm(
    const float* __restrict__ word, const int* __restrict__ labels,
    const float* __restrict__ emb, const float* __restrict__ w_ih,
    const float* __restrict__ b_ih, float* __restrict__ gxC, int t0)
{
  __shared__ float xs[2][32][72];    // [k][b], padded
  __shared__ float wsm[2][32][136];  // [k][c], padded

  const int bid = blockIdx.x;
  const int Tl = bid / 24;           // 0..C_-1
  const int T  = t0 + Tl;            // global t
  const int cb = bid % 24;
  const int tid = threadIdx.x;

  const int xb = tid >> 2, xkq = tid & 3;           // x: 8 k's per thread
  const int pid = (T > 0) ? labels[xb * S_ + T - 1] : 0;
  const float* xsrcA = emb + (size_t)pid * E_;                   // k in [0,128)
  const float* xsrcB = word + ((size_t)xb * S_ + T) * H_ - E_;   // k in [128,1152)
  const int wc = tid >> 1, wkh = tid & 1;           // w: 16 k's per thread
  const float* wrow = w_ih + (size_t)(cb * 128 + wc) * K_;

  float4 xr0, xr1, wr0, wr1, wr2, wr3;

  auto load_tile = [&](int kt) {
    const int kg = kt * 32;
    const float* xsrc = (kg < E_) ? (xsrcA + kg) : (xsrcB + kg);
    xr0 = *(const float4*)(xsrc + xkq * 8);
    xr1 = *(const float4*)(xsrc + xkq * 8 + 4);
    const float* wsrc = wrow + kg + wkh * 16;
    wr0 = *(const float4*)(wsrc);
    wr1 = *(const float4*)(wsrc + 4);
    wr2 = *(const float4*)(wsrc + 8);
    wr3 = *(const float4*)(wsrc + 12);
  };
  auto store_tile = [&](int bf) {
#pragma unroll
    for (int i = 0; i < 4; ++i) xs[bf][xkq * 8 + i][xb]     = ((const float*)&xr0)[i];
#pragma unroll
    for (int i = 0; i < 4; ++i) xs[bf][xkq * 8 + 4 + i][xb] = ((const float*)&xr1)[i];
#pragma unroll
    for (int i = 0; i < 4; ++i) wsm[bf][wkh * 16 + i][wc]      = ((const float*)&wr0)[i];
#pragma unroll
    for (int i = 0; i < 4; ++i) wsm[bf][wkh * 16 + 4 + i][wc]  = ((const float*)&wr1)[i];
#pragma unroll
    for (int i = 0; i < 4; ++i) wsm[bf][wkh * 16 + 8 + i][wc]  = ((const float*)&wr2)[i];
#pragma unroll
    for (int i = 0; i < 4; ++i) wsm[bf][wkh * 16 + 12 + i][wc] = ((const float*)&wr3)[i];
  };

  const int cg = tid >> 4, bg = tid & 15;   // thread: 8 c's x 4 b's
  float acc[8][4];
#pragma unroll
  for (int i = 0; i < 8; ++i)
#pragma unroll
    for (int j = 0; j < 4; ++j) acc[i][j] = 0.f;

  load_tile(0);
  store_tile(0);
  __syncthreads();

  for (int kt = 0; kt < 36; ++kt) {
    const int cur = kt & 1;
    if (kt < 35) load_tile(kt + 1);   // global prefetch overlaps compute
#pragma unroll 4
    for (int k = 0; k < 32; ++k) {
      const float4 xv  = *(const float4*)&xs[cur][k][bg * 4];
      const float4 wv0 = *(const float4*)&wsm[cur][k][cg * 8];
      const float4 wv1 = *(const float4*)&wsm[cur][k][cg * 8 + 4];
      const float wv[8] = {wv0.x, wv0.y, wv0.z, wv0.w, wv1.x, wv1.y, wv1.z, wv1.w};
      const float xa[4] = {xv.x, xv.y, xv.z, xv.w};
#pragma unroll
      for (int ci = 0; ci < 8; ++ci)
#pragma unroll
        for (int bi = 0; bi < 4; ++bi)
          acc[ci][bi] = fmaf(wv[ci], xa[bi], acc[ci][bi]);
    }
    if (kt < 35) store_tile(cur ^ 1);
    __syncthreads();
  }

  const size_t obase = ((size_t)Tl * G3_ + (size_t)cb * 128) * 64;
#pragma unroll
  for (int ci = 0; ci < 8; ++ci) {
    const int c = cg * 8 + ci;
    const float bv = b_ih[cb * 128 + c];
    float4 o;
    o.x = acc[ci][0] + bv; o.y = acc[ci][1] + bv;
    o.z = acc[ci][2] + bv; o.w = acc[ci][3] + bv;
    *(float4*)&gxC[obase + (size_t)c * 64 + bg * 4] = o;
  }
}

// ---------------------------------------------------------------------------
// Two-level grid barrier (16 groups x 16 WGs), agent-scope atomics.
// Safe: grid=256 at 1 WG/CU (LDS>80KB) on 256 CUs -> all co-resident.
// Generation counter `gen` is monotone across chunk launches.
// ---------------------------------------------------------------------------
__device__ __forceinline__ void grid_barrier(unsigned* bar, unsigned target, int wg)
{
  __syncthreads();
  if (threadIdx.x == 0) {
    unsigned* grp  = bar + (wg & 15) * 32;
    unsigned* root = bar + 512;
    unsigned* gen  = bar + 544;
    const unsigned old =
        __hip_atomic_fetch_add(grp, 1u, __ATOMIC_ACQ_REL, __HIP_MEMORY_SCOPE_AGENT);
    if (old == 15u) {
      const unsigned r =
          __hip_atomic_fetch_add(root, 1u, __ATOMIC_ACQ_REL, __HIP_MEMORY_SCOPE_AGENT);
      if (r == 15u) {
#pragma unroll
        for (int i = 0; i < 16; ++i)
          __hip_atomic_store(bar + i * 32, 0u, __ATOMIC_RELAXED, __HIP_MEMORY_SCOPE_AGENT);
        __hip_atomic_store(root, 0u, __ATOMIC_RELAXED, __HIP_MEMORY_SCOPE_AGENT);
        __hip_atomic_store(gen, target, __ATOMIC_RELEASE, __HIP_MEMORY_SCOPE_AGENT);
      }
    }
    while (__hip_atomic_load(gen, __ATOMIC_RELAXED, __HIP_MEMORY_SCOPE_AGENT) < target)
      __builtin_amdgcn_s_sleep(2);
    (void)__hip_atomic_load(gen, __ATOMIC_ACQUIRE, __HIP_MEMORY_SCOPE_AGENT);
  }
  __syncthreads();
}

// ---------------------------------------------------------------------------
// Phase 2 (per chunk): sequential GRU scan, C_ steps. 256 WGs x 512 thr, 1/CU.
// WG g owns h-cols j in [4g,4g+4) (gate rows j, 1024+j, 2048+j).
// w_hh slice (12x1024, 48KB) in LDS for the whole chunk.
// K split across 8 waves. *** v2: h k-slice register-prefetched per step ***
// (128 independent global loads issued up front -> one latency exposure,
// then fully-unrolled FMA loop: weights = LDS b128 broadcast, h = VGPRs).
// h layout [k][b]; outsC layout [t_local][k][b].
// ---------------------------------------------------------------------------
__global__ __launch_bounds__(512, 1) void scan_kernel(
    const float* __restrict__ gxC, const float* __restrict__ w_hh,
    const float* __restrict__ b_hh, float* hA, float* hB,
    float* __restrict__ outsC, unsigned* bar, unsigned step0)
{
  __shared__ float wsm[12 * 1024];     // 48KB  [c_local][k]
  __shared__ float red[8][17][64];     // 34.8KB -> total ~84KB -> 1 WG/CU
  const int g = blockIdx.x;
  const int tid = threadIdx.x;
  const int lane = tid & 63;
  const int wave = tid >> 6;

  for (int idx = tid; idx < 3072; idx += 512) {
    const int c = idx >> 8;          // local row 0..11 = gate*4 + jj
    const int k4 = idx & 255;
    const int gate = c >> 2, jj = c & 3;
    *(float4*)&wsm[c * 1024 + (k4 << 2)] =
        *(const float4*)&w_hh[(size_t)(gate * 1024 + g * 4 + jj) * 1024 + (k4 << 2)];
  }

  float bhr = 0.f, bhz = 0.f, bhn = 0.f;
  int j = 0, b = 0;
  if (tid < 256) {
    b = tid & 63;
    const int jj = tid >> 6;
    j = g * 4 + jj;
    bhr = b_hh[j]; bhz = b_hh[1024 + j]; bhn = b_hh[2048 + j];
  }
  __syncthreads();

  float* hcur = hA;
  float* hnxt = hB;
  const int k0 = wave << 7;

  for (int s = 0; s < C_; ++s) {
    // independent prefetches (gate inputs + previous h for the z-blend)
    float gxr = 0.f, gxz = 0.f, gxn = 0.f, hold = 0.f;
    if (tid < 256) {
      const size_t gb = (size_t)s * G3_ * 64;
      gxr  = gxC[gb + (size_t)j * 64 + b];
      gxz  = gxC[gb + (size_t)(1024 + j) * 64 + b];
      gxn  = gxC[gb + (size_t)(2048 + j) * 64 + b];
      hold = hcur[(j << 6) + b];
    }

    // v2: issue ALL 128 h loads for this wave's k-slice up front (independent,
    // coalesced 256B/instr), static-indexed -> VGPRs. One latency exposure.
    float hreg[128];
    const float* hq = hcur + (k0 << 6) + lane;
#pragma unroll
    for (int kk = 0; kk < 128; ++kk) hreg[kk] = hq[kk << 6];

    // fully-unrolled matvec: 12 gate rows x 128 k. Weights via b128 broadcast.
    float acc[12];
#pragma unroll
    for (int c = 0; c < 12; ++c) acc[c] = 0.f;
#pragma unroll
    for (int kk = 0; kk < 128; kk += 4) {
#pragma unroll
      for (int c = 0; c < 12; ++c) {
        const float4 w = *(const float4*)&wsm[c * 1024 + k0 + kk];
        acc[c] = fmaf(w.w, hreg[kk + 3],
                 fmaf(w.z, hreg[kk + 2],
                 fmaf(w.y, hreg[kk + 1],
                 fmaf(w.x, hreg[kk], acc[c]))));
      }
    }
#pragma unroll
    for (int c = 0; c < 12; ++c) red[wave][c][lane] = acc[c];
    __syncthreads();

    if (tid < 256) {
      const int jj = tid >> 6;
      float rs = 0.f, zs = 0.f, ns = 0.f;
#pragma unroll
      for (int w = 0; w < 8; ++w) {
        rs += red[w][jj][b];
        zs += red[w][4 + jj][b];
        ns += red[w][8 + jj][b];
      }
      const float r = 1.0f / (1.0f + expf(-(gxr + rs + bhr)));
      const float z = 1.0f / (1.0f + expf(-(gxz + zs + bhz)));
      const float n = tanhf(gxn + r * (ns + bhn));
      const float hnew = (1.0f - z) * n + z * hold;
      __hip_atomic_store(&hnxt[(j << 6) + b], hnew, __ATOMIC_RELAXED, __HIP_MEMORY_SCOPE_AGENT);
      outsC[((size_t)s << 16) + (j << 6) + b] = hnew;
    }
    grid_barrier(bar, step0 + (unsigned)s + 1u, g);
    float* t_ = hcur; hcur = hnxt; hnxt = t_;
  }
}

// ---------------------------------------------------------------------------
// Phase 3 (per chunk): logits[b,t,l] = outsC[tl,:,b].w_out[l,:] + b_out[l],
// IOBES-masked from prev label. One WG per t_local.
// ---------------------------------------------------------------------------
__global__ __launch_bounds__(256) void logits_kernel(
    const float* __restrict__ outsC, const int* __restrict__ labels,
    const float* __restrict__ w_out, const float* __restrict__ b_out,
    float* __restrict__ out, int t0)
{
  __shared__ float hs[128 * 64];
  __shared__ float wso[49 * 128];
  const int tl = blockIdx.x;
  const int t  = t0 + tl;
  const int tid = threadIdx.x;
  const int b = tid & 63, lq = tid >> 6;
  const int l0 = lq * 13;
  const int nl = (lq == 3) ? 10 : 13;

  float acc[13];
#pragma unroll
  for (int i = 0; i < 13; ++i) acc[i] = 0.f;

  for (int kc = 0; kc < 8; ++kc) {
    __syncthreads();
#pragma unroll
    for (int i = 0; i < 8; ++i) {
      const int flat = (i << 10) + (tid << 2);
      *(float4*)&hs[flat] = *(const float4*)&outsC[((size_t)tl << 16) + (kc << 13) + flat];
    }
    for (int idx = tid; idx < 1568; idx += 256) {
      const int l = idx >> 5, k4 = idx & 31;
      *(float4*)&wso[l * 128 + (k4 << 2)] =
          *(const float4*)&w_out[(size_t)l * 1024 + (kc << 7) + (k4 << 2)];
    }
    __syncthreads();
    for (int k = 0; k < 128; k += 4) {
      const float h0 = hs[((k + 0) << 6) + b];
      const float h1 = hs[((k + 1) << 6) + b];
      const float h2 = hs[((k + 2) << 6) + b];
      const float h3 = hs[((k + 3) << 6) + b];
#pragma unroll
      for (int li = 0; li < 13; ++li) {
        if (li < nl) {
          const float4 w = *(const float4*)&wso[(l0 + li) * 128 + k];
          acc[li] = fmaf(w.w, h3, fmaf(w.z, h2, fmaf(w.y, h1, fmaf(w.x, h0, acc[li]))));
        }
      }
    }
  }

  const int pid = (t > 0) ? labels[b * S_ + t - 1] : 0;
  bool prevOES;
  int ptype = 0;
  if (pid == 0) { prevOES = true; }
  else {
    const int pp = (pid - 1) & 3;   // 0:B 1:I 2:E 3:S
    prevOES = (pp >= 2);
    ptype = (pid - 1) >> 2;
  }
#pragma unroll
  for (int li = 0; li < 13; ++li) {
    if (li < nl) {
      const int l = l0 + li;
      bool ok;
      if (prevOES) {
        ok = (l == 0) || (((l - 1) & 3) == 0) || (((l - 1) & 3) == 3);  // O, B-*, S-*
      } else {
        ok = (l > 0) && (((l - 1) >> 2) == ptype) &&
             ((((l - 1) & 3) == 1) || (((l - 1) & 3) == 2));            // I-T, E-T
      }
      out[(((size_t)b << 9) + t) * 49 + l] = ok ? (acc[li] + b_out[l]) : -1e12f;
    }
  }
}

// ---------------------------------------------------------------------------
// ws layout (total 64.5 MB):
//   gxC   @ 0          : 50,331,648 B   [C_][3072][64] f32
//   outsC @ 50,331,648 : 16,777,216 B   [C_][1024][64] f32
//   hA    @ 67,108,864 :    262,144 B
//   hB    @ 67,371,008 :    262,144 B
//   bar   @ 67,633,152 :      4,096 B
// ---------------------------------------------------------------------------
extern "C" void kernel_launch(void* const* d_in, const int* in_sizes, int n_in,
                              void* d_out, int out_size, void* d_ws, size_t ws_size,
                              hipStream_t stream)
{
  const float* word   = (const float*)d_in[0];
  const int*   labels = (const int*)d_in[1];
  const float* emb    = (const float*)d_in[2];
  const float* w_ih   = (const float*)d_in[3];
  const float* w_hh   = (const float*)d_in[4];
  const float* b_ih   = (const float*)d_in[5];
  const float* b_hh   = (const float*)d_in[6];
  const float* w_out  = (const float*)d_in[7];
  const float* b_out  = (const float*)d_in[8];
  float* out = (float*)d_out;

  char* ws = (char*)d_ws;
  float*    gxC   = (float*)ws;
  float*    outsC = (float*)(ws + 50331648ull);
  float*    hA    = (float*)(ws + 67108864ull);
  float*    hB    = (float*)(ws + 67371008ull);
  unsigned* bar   = (unsigned*)(ws + 67633152ull);

  init_kernel<<<dim3(129), dim3(256), 0, stream>>>((float4*)hA);  // hA,hB,bar = 0

  for (int ch = 0; ch < NCH_; ++ch) {
    const int t0 = ch * C_;
    gx_gemm<<<dim3(C_ * 24), dim3(256), 0, stream>>>(word, labels, emb, w_ih, b_ih,
                                                     gxC, t0);
    scan_kernel<<<dim3(256), dim3(512), 0, stream>>>(gxC, w_hh, b_hh, hA, hB,
                                                     outsC, bar, (unsigned)t0);
    logits_kernel<<<dim3(C_), dim3(256), 0, stream>>>(outsC, labels, w_out, b_out,
                                                      out, t0);
  }
}

// Round 4
// 12677.876 us; speedup vs baseline: 1.0788x; 1.0319x over previous
//
#include <hip/hip_runtime.h>
#include <cstdint>
#include <cstddef>

#define B_ 64
#define S_ 512
#define H_ 1024
#define E_ 128
#define L_ 49
#define G3_ 3072   // 3*H
#define K_ 1152    // E+H
#define C_ 64      // chunk length (steps) -- even, so h state round-trips to hA
#define NCH_ 8     // 512 / C_

// ---------------------------------------------------------------------------
// init: zero h buffers + barrier state (hA,hB,bar contiguous = 528384 B exact)
// ---------------------------------------------------------------------------
__global__ __launch_bounds__(256) void init_kernel(float4* __restrict__ p)
{
  const int i = blockIdx.x * 256 + threadIdx.x;   // grid 129*256 = 33024 exact
  p[i] = make_float4(0.f, 0.f, 0.f, 0.f);
}

// ---------------------------------------------------------------------------
// Phase 1 (per chunk): gxC[tl][c][b] = sum_i x[b,t0+tl,i]*w_ih[c,i] + b_ih[c]
// (unchanged from round 3)
// ---------------------------------------------------------------------------
__global__ __launch_bounds__(256) void gx_gemm(
    const float* __restrict__ word, const int* __restrict__ labels,
    const float* __restrict__ emb, const float* __restrict__ w_ih,
    const float* __restrict__ b_ih, float* __restrict__ gxC, int t0)
{
  __shared__ float xs[2][32][72];    // [k][b], padded
  __shared__ float wsm[2][32][136];  // [k][c], padded

  const int bid = blockIdx.x;
  const int Tl = bid / 24;           // 0..C_-1
  const int T  = t0 + Tl;            // global t
  const int cb = bid % 24;
  const int tid = threadIdx.x;

  const int xb = tid >> 2, xkq = tid & 3;           // x: 8 k's per thread
  const int pid = (T > 0) ? labels[xb * S_ + T - 1] : 0;
  const float* xsrcA = emb + (size_t)pid * E_;                   // k in [0,128)
  const float* xsrcB = word + ((size_t)xb * S_ + T) * H_ - E_;   // k in [128,1152)
  const int wc = tid >> 1, wkh = tid & 1;           // w: 16 k's per thread
  const float* wrow = w_ih + (size_t)(cb * 128 + wc) * K_;

  float4 xr0, xr1, wr0, wr1, wr2, wr3;

  auto load_tile = [&](int kt) {
    const int kg = kt * 32;
    const float* xsrc = (kg < E_) ? (xsrcA + kg) : (xsrcB + kg);
    xr0 = *(const float4*)(xsrc + xkq * 8);
    xr1 = *(const float4*)(xsrc + xkq * 8 + 4);
    const float* wsrc = wrow + kg + wkh * 16;
    wr0 = *(const float4*)(wsrc);
    wr1 = *(const float4*)(wsrc + 4);
    wr2 = *(const float4*)(wsrc + 8);
    wr3 = *(const float4*)(wsrc + 12);
  };
  auto store_tile = [&](int bf) {
#pragma unroll
    for (int i = 0; i < 4; ++i) xs[bf][xkq * 8 + i][xb]     = ((const float*)&xr0)[i];
#pragma unroll
    for (int i = 0; i < 4; ++i) xs[bf][xkq * 8 + 4 + i][xb] = ((const float*)&xr1)[i];
#pragma unroll
    for (int i = 0; i < 4; ++i) wsm[bf][wkh * 16 + i][wc]      = ((const float*)&wr0)[i];
#pragma unroll
    for (int i = 0; i < 4; ++i) wsm[bf][wkh * 16 + 4 + i][wc]  = ((const float*)&wr1)[i];
#pragma unroll
    for (int i = 0; i < 4; ++i) wsm[bf][wkh * 16 + 8 + i][wc]  = ((const float*)&wr2)[i];
#pragma unroll
    for (int i = 0; i < 4; ++i) wsm[bf][wkh * 16 + 12 + i][wc] = ((const float*)&wr3)[i];
  };

  const int cg = tid >> 4, bg = tid & 15;   // thread: 8 c's x 4 b's
  float acc[8][4];
#pragma unroll
  for (int i = 0; i < 8; ++i)
#pragma unroll
    for (int j = 0; j < 4; ++j) acc[i][j] = 0.f;

  load_tile(0);
  store_tile(0);
  __syncthreads();

  for (int kt = 0; kt < 36; ++kt) {
    const int cur = kt & 1;
    if (kt < 35) load_tile(kt + 1);   // global prefetch overlaps compute
#pragma unroll 4
    for (int k = 0; k < 32; ++k) {
      const float4 xv  = *(const float4*)&xs[cur][k][bg * 4];
      const float4 wv0 = *(const float4*)&wsm[cur][k][cg * 8];
      const float4 wv1 = *(const float4*)&wsm[cur][k][cg * 8 + 4];
      const float wv[8] = {wv0.x, wv0.y, wv0.z, wv0.w, wv1.x, wv1.y, wv1.z, wv1.w};
      const float xa[4] = {xv.x, xv.y, xv.z, xv.w};
#pragma unroll
      for (int ci = 0; ci < 8; ++ci)
#pragma unroll
        for (int bi = 0; bi < 4; ++bi)
          acc[ci][bi] = fmaf(wv[ci], xa[bi], acc[ci][bi]);
    }
    if (kt < 35) store_tile(cur ^ 1);
    __syncthreads();
  }

  const size_t obase = ((size_t)Tl * G3_ + (size_t)cb * 128) * 64;
#pragma unroll
  for (int ci = 0; ci < 8; ++ci) {
    const int c = cg * 8 + ci;
    const float bv = b_ih[cb * 128 + c];
    float4 o;
    o.x = acc[ci][0] + bv; o.y = acc[ci][1] + bv;
    o.z = acc[ci][2] + bv; o.w = acc[ci][3] + bv;
    *(float4*)&gxC[obase + (size_t)c * 64 + bg * 4] = o;
  }
}

// ---------------------------------------------------------------------------
// Phase 2 (per chunk): GRU scan v3.
//  * 1024 threads (16 waves), each wave owns a 64-k slice -> hreg[64] fits
//    in <=128 VGPRs (16 waves/CU), 4 waves/SIMD TLP.
//  * w_hh read via SCALAR loads (wave-uniform addresses through
//    readfirstlane) -> K$/L2 path, zero LDS broadcast (the round-2/3
//    bottleneck: 3072 uniform-address ds_read_b128/step = ~15 us/step).
//  * h exchange: relaxed agent-scope atomics (sc0/sc1, L1/L2-bypass, always
//    fresh at L3) -> the grid barrier needs NO acquire/release cache ops ->
//    no per-step L2 invalidate; gxC stays L2-resident.
//  * single-counter relaxed barrier + monotone generation word.
// Ordering argument: __syncthreads() drains each wave's vmcnt before
// s_barrier, so all h sc1-stores are at L3 before any thread arrives.
// ---------------------------------------------------------------------------
__global__ __launch_bounds__(1024, 4) void scan_kernel(
    const float* __restrict__ gxC, const float* __restrict__ w_hh,
    const float* __restrict__ b_hh, float* hA, float* hB,
    float* __restrict__ outsC, unsigned* bar, unsigned step0)
{
  __shared__ float red[16][12][64];   // 48 KB cross-wave partials
  __shared__ float lds_pad[8704];     // -> 83968 B total: forces 1 WG/CU

  const int g = blockIdx.x;
  const int tid = threadIdx.x;
  const int lane = tid & 63;
  const int wave = tid >> 6;
  const int k0u = __builtin_amdgcn_readfirstlane(wave << 6);  // wave-uniform

  if ((int)blockIdx.x < 0) { lds_pad[tid] = 1.f; __syncthreads(); }  // keep pad

  // uniform row pointers -> scalar (s_load) weight reads
  const float* wrow[12];
#pragma unroll
  for (int c = 0; c < 12; ++c)
    wrow[c] = w_hh + (size_t)((c >> 2) * 1024 + g * 4 + (c & 3)) * 1024 + k0u;

  float bhr = 0.f, bhz = 0.f, bhn = 0.f, hold = 0.f;
  float gxr = 0.f, gxz = 0.f, gxn = 0.f;
  int j = 0, b = 0;
  if (tid < 256) {
    b = tid & 63;
    const int jj = tid >> 6;
    j = g * 4 + jj;
    bhr = b_hh[j]; bhz = b_hh[1024 + j]; bhn = b_hh[2048 + j];
    hold = __hip_atomic_load(&hA[(j << 6) + b], __ATOMIC_RELAXED,
                             __HIP_MEMORY_SCOPE_AGENT);      // chunk-carry h
    gxr = gxC[(size_t)j * 64 + b];                           // s = 0
    gxz = gxC[(size_t)(1024 + j) * 64 + b];
    gxn = gxC[(size_t)(2048 + j) * 64 + b];
  }

  float* hcur = hA;
  float* hnxt = hB;
  unsigned* cnt = bar;
  unsigned* gen = bar + 544;

  for (int s = 0; s < C_; ++s) {
    // ---- h k-slice -> registers (sc1: fresh from L3, coalesced 256B/instr)
    float hreg[64];
    {
      float* hq = hcur + ((size_t)k0u << 6) + lane;
#pragma unroll
      for (int kk = 0; kk < 64; ++kk)
        hreg[kk] = __hip_atomic_load(&hq[kk << 6], __ATOMIC_RELAXED,
                                     __HIP_MEMORY_SCOPE_AGENT);
    }
    // ---- prefetch next step's gate inputs (independent of h, L2-cached)
    float ngxr = 0.f, ngxz = 0.f, ngxn = 0.f;
    if (tid < 256 && s + 1 < C_) {
      const size_t gb = (size_t)(s + 1) * G3_ * 64;
      ngxr = gxC[gb + (size_t)j * 64 + b];
      ngxz = gxC[gb + (size_t)(1024 + j) * 64 + b];
      ngxn = gxC[gb + (size_t)(2048 + j) * 64 + b];
    }
    // ---- matvec: 12 gate rows x 64 k; w via scalar loads, h from VGPRs
    float acc[12];
#pragma unroll
    for (int c = 0; c < 12; ++c) acc[c] = 0.f;
#pragma unroll
    for (int cq = 0; cq < 3; ++cq)          // row quads: 4 acc chains live
#pragma unroll
      for (int kc = 0; kc < 64; kc += 16)   // 16-wide w chunks (SGPR stream)
#pragma unroll
        for (int i = 0; i < 16; ++i)
#pragma unroll
          for (int r = 0; r < 4; ++r)
            acc[cq * 4 + r] =
                fmaf(wrow[cq * 4 + r][kc + i], hreg[kc + i], acc[cq * 4 + r]);
#pragma unroll
    for (int c = 0; c < 12; ++c) red[wave][c][lane] = acc[c];
    __syncthreads();

    // ---- reduce 16 waves + gate math (first 4 waves)
    if (tid < 256) {
      const int jj = tid >> 6;
      float rs = 0.f, zs = 0.f, ns = 0.f;
#pragma unroll
      for (int w = 0; w < 16; ++w) {
        rs += red[w][jj][b];
        zs += red[w][4 + jj][b];
        ns += red[w][8 + jj][b];
      }
      const float r = 1.0f / (1.0f + expf(-(gxr + rs + bhr)));
      const float z = 1.0f / (1.0f + expf(-(gxz + zs + bhz)));
      const float n = tanhf(gxn + r * (ns + bhn));
      const float hnew = (1.0f - z) * n + z * hold;
      __hip_atomic_store(&hnxt[(j << 6) + b], hnew, __ATOMIC_RELAXED,
                         __HIP_MEMORY_SCOPE_AGENT);          // sc1 -> L3
      outsC[((size_t)s << 16) + (j << 6) + b] = hnew;        // cached, kernel-end flush
      hold = hnew;                                           // carry own h
      gxr = ngxr; gxz = ngxz; gxn = ngxn;
    }

    // ---- relaxed grid barrier (no cache maintenance)
    __syncthreads();   // per-wave vmcnt(0) drain: all h stores at L3 here
    if (tid == 0) {
      asm volatile("s_waitcnt vmcnt(0)" ::: "memory");
      const unsigned tgt = step0 + (unsigned)s + 1u;
      const unsigned old =
          __hip_atomic_fetch_add(cnt, 1u, __ATOMIC_RELAXED, __HIP_MEMORY_SCOPE_AGENT);
      if (old == 255u) {
        __hip_atomic_store(cnt, 0u, __ATOMIC_RELAXED, __HIP_MEMORY_SCOPE_AGENT);
        asm volatile("s_waitcnt vmcnt(0)" ::: "memory");     // reset before release
        __hip_atomic_store(gen, tgt, __ATOMIC_RELAXED, __HIP_MEMORY_SCOPE_AGENT);
      } else {
        while (__hip_atomic_load(gen, __ATOMIC_RELAXED, __HIP_MEMORY_SCOPE_AGENT) < tgt)
          __builtin_amdgcn_s_sleep(1);
      }
    }
    __syncthreads();
    float* t_ = hcur; hcur = hnxt; hnxt = t_;
  }
}

// ---------------------------------------------------------------------------
// Phase 3 (per chunk): logits + IOBES mask (unchanged)
// ---------------------------------------------------------------------------
__global__ __launch_bounds__(256) void logits_kernel(
    const float* __restrict__ outsC, const int* __restrict__ labels,
    const float* __restrict__ w_out, const float* __restrict__ b_out,
    float* __restrict__ out, int t0)
{
  __shared__ float hs[128 * 64];
  __shared__ float wso[49 * 128];
  const int tl = blockIdx.x;
  const int t  = t0 + tl;
  const int tid = threadIdx.x;
  const int b = tid & 63, lq = tid >> 6;
  const int l0 = lq * 13;
  const int nl = (lq == 3) ? 10 : 13;

  float acc[13];
#pragma unroll
  for (int i = 0; i < 13; ++i) acc[i] = 0.f;

  for (int kc = 0; kc < 8; ++kc) {
    __syncthreads();
#pragma unroll
    for (int i = 0; i < 8; ++i) {
      const int flat = (i << 10) + (tid << 2);
      *(float4*)&hs[flat] = *(const float4*)&outsC[((size_t)tl << 16) + (kc << 13) + flat];
    }
    for (int idx = tid; idx < 1568; idx += 256) {
      const int l = idx >> 5, k4 = idx & 31;
      *(float4*)&wso[l * 128 + (k4 << 2)] =
          *(const float4*)&w_out[(size_t)l * 1024 + (kc << 7) + (k4 << 2)];
    }
    __syncthreads();
    for (int k = 0; k < 128; k += 4) {
      const float h0 = hs[((k + 0) << 6) + b];
      const float h1 = hs[((k + 1) << 6) + b];
      const float h2 = hs[((k + 2) << 6) + b];
      const float h3 = hs[((k + 3) << 6) + b];
#pragma unroll
      for (int li = 0; li < 13; ++li) {
        if (li < nl) {
          const float4 w = *(const float4*)&wso[(l0 + li) * 128 + k];
          acc[li] = fmaf(w.w, h3, fmaf(w.z, h2, fmaf(w.y, h1, fmaf(w.x, h0, acc[li]))));
        }
      }
    }
  }

  const int pid = (t > 0) ? labels[b * S_ + t - 1] : 0;
  bool prevOES;
  int ptype = 0;
  if (pid == 0) { prevOES = true; }
  else {
    const int pp = (pid - 1) & 3;   // 0:B 1:I 2:E 3:S
    prevOES = (pp >= 2);
    ptype = (pid - 1) >> 2;
  }
#pragma unroll
  for (int li = 0; li < 13; ++li) {
    if (li < nl) {
      const int l = l0 + li;
      bool ok;
      if (prevOES) {
        ok = (l == 0) || (((l - 1) & 3) == 0) || (((l - 1) & 3) == 3);  // O, B-*, S-*
      } else {
        ok = (l > 0) && (((l - 1) >> 2) == ptype) &&
             ((((l - 1) & 3) == 1) || (((l - 1) & 3) == 2));            // I-T, E-T
      }
      out[(((size_t)b << 9) + t) * 49 + l] = ok ? (acc[li] + b_out[l]) : -1e12f;
    }
  }
}

// ---------------------------------------------------------------------------
// ws layout (total 64.5 MB):
//   gxC   @ 0          : 50,331,648 B   [C_][3072][64] f32
//   outsC @ 50,331,648 : 16,777,216 B   [C_][1024][64] f32
//   hA    @ 67,108,864 :    262,144 B
//   hB    @ 67,371,008 :    262,144 B
//   bar   @ 67,633,152 :      4,096 B   (cnt @ +0, gen @ +544 dwords)
// ---------------------------------------------------------------------------
extern "C" void kernel_launch(void* const* d_in, const int* in_sizes, int n_in,
                              void* d_out, int out_size, void* d_ws, size_t ws_size,
                              hipStream_t stream)
{
  const float* word   = (const float*)d_in[0];
  const int*   labels = (const int*)d_in[1];
  const float* emb    = (const float*)d_in[2];
  const float* w_ih   = (const float*)d_in[3];
  const float* w_hh   = (const float*)d_in[4];
  const float* b_ih   = (const float*)d_in[5];
  const float* b_hh   = (const float*)d_in[6];
  const float* w_out  = (const float*)d_in[7];
  const float* b_out  = (const float*)d_in[8];
  float* out = (float*)d_out;

  char* ws = (char*)d_ws;
  float*    gxC   = (float*)ws;
  float*    outsC = (float*)(ws + 50331648ull);
  float*    hA    = (float*)(ws + 67108864ull);
  float*    hB    = (float*)(ws + 67371008ull);
  unsigned* bar   = (unsigned*)(ws + 67633152ull);

  init_kernel<<<dim3(129), dim3(256), 0, stream>>>((float4*)hA);  // hA,hB,bar = 0

  for (int ch = 0; ch < NCH_; ++ch) {
    const int t0 = ch * C_;
    gx_gemm<<<dim3(C_ * 24), dim3(256), 0, stream>>>(word, labels, emb, w_ih, b_ih,
                                                     gxC, t0);
    scan_kernel<<<dim3(256), dim3(1024), 0, stream>>>(gxC, w_hh, b_hh, hA, hB,
                                                      outsC, bar, (unsigned)t0);
    logits_kernel<<<dim3(C_), dim3(256), 0, stream>>>(outsC, labels, w_out, b_out,
                                                      out, t0);
  }
}

// Round 5
// 8331.812 us; speedup vs baseline: 1.6416x; 1.5216x over previous
//
#include <hip/hip_runtime.h>
#include <cstdint>
#include <cstddef>

#define B_ 64
#define S_ 512
#define H_ 1024
#define E_ 128
#define L_ 49
#define G3_ 3072   // 3*H
#define K_ 1152    // E+H
#define C_ 64      // chunk length (steps), even
#define NCH_ 8     // 512 / C_

typedef short bf16x8 __attribute__((ext_vector_type(8)));
typedef float f32x4 __attribute__((ext_vector_type(4)));
typedef unsigned int u32x2 __attribute__((ext_vector_type(2)));

// bf16 round-to-nearest-even helpers (no NaN inputs here)
__device__ __forceinline__ unsigned short f2bf(float f) {
  unsigned int u = __builtin_bit_cast(unsigned int, f);
  return (unsigned short)((u + 0x7FFFu + ((u >> 16) & 1u)) >> 16);
}
__device__ __forceinline__ float bf2f(unsigned short h) {
  unsigned int u = ((unsigned int)h) << 16;
  return __builtin_bit_cast(float, u);
}

// coherent (L1/L2-bypass, L3-fresh) asm memory ops
#define GLOAD16(dst, a64) asm volatile("global_load_dwordx4 %0, %1, off sc0 sc1" : "=v"(dst) : "v"(a64))
#define GLOAD8(dst, a64)  asm volatile("global_load_dwordx2 %0, %1, off sc0 sc1" : "=v"(dst) : "v"(a64))
#define GSTORE8(a64, v2)  asm volatile("global_store_dwordx2 %0, %1, off sc0 sc1" :: "v"(a64), "v"(v2) : "memory")
#define WAITV(N) asm volatile("s_waitcnt vmcnt(" #N ")")

// ---------------------------------------------------------------------------
// init: zero bf16 h-planes (4x128KB) + barrier state = 528384 B exact
// ---------------------------------------------------------------------------
__global__ __launch_bounds__(256) void init_kernel(float4* __restrict__ p)
{
  const int i = blockIdx.x * 256 + threadIdx.x;   // grid 129*256 = 33024 exact
  p[i] = make_float4(0.f, 0.f, 0.f, 0.f);
}

// ---------------------------------------------------------------------------
// Phase 1 (per chunk): gxC[tl][c][b] (unchanged from round 3/4)
// ---------------------------------------------------------------------------
__global__ __launch_bounds__(256) void gx_gemm(
    const float* __restrict__ word, const int* __restrict__ labels,
    const float* __restrict__ emb, const float* __restrict__ w_ih,
    const float* __restrict__ b_ih, float* __restrict__ gxC, int t0)
{
  __shared__ float xs[2][32][72];
  __shared__ float wsm[2][32][136];

  const int bid = blockIdx.x;
  const int Tl = bid / 24;
  const int T  = t0 + Tl;
  const int cb = bid % 24;
  const int tid = threadIdx.x;

  const int xb = tid >> 2, xkq = tid & 3;
  const int pid = (T > 0) ? labels[xb * S_ + T - 1] : 0;
  const float* xsrcA = emb + (size_t)pid * E_;
  const float* xsrcB = word + ((size_t)xb * S_ + T) * H_ - E_;
  const int wc = tid >> 1, wkh = tid & 1;
  const float* wrow = w_ih + (size_t)(cb * 128 + wc) * K_;

  float4 xr0, xr1, wr0, wr1, wr2, wr3;

  auto load_tile = [&](int kt) {
    const int kg = kt * 32;
    const float* xsrc = (kg < E_) ? (xsrcA + kg) : (xsrcB + kg);
    xr0 = *(const float4*)(xsrc + xkq * 8);
    xr1 = *(const float4*)(xsrc + xkq * 8 + 4);
    const float* wsrc = wrow + kg + wkh * 16;
    wr0 = *(const float4*)(wsrc);
    wr1 = *(const float4*)(wsrc + 4);
    wr2 = *(const float4*)(wsrc + 8);
    wr3 = *(const float4*)(wsrc + 12);
  };
  auto store_tile = [&](int bf) {
#pragma unroll
    for (int i = 0; i < 4; ++i) xs[bf][xkq * 8 + i][xb]     = ((const float*)&xr0)[i];
#pragma unroll
    for (int i = 0; i < 4; ++i) xs[bf][xkq * 8 + 4 + i][xb] = ((const float*)&xr1)[i];
#pragma unroll
    for (int i = 0; i < 4; ++i) wsm[bf][wkh * 16 + i][wc]      = ((const float*)&wr0)[i];
#pragma unroll
    for (int i = 0; i < 4; ++i) wsm[bf][wkh * 16 + 4 + i][wc]  = ((const float*)&wr1)[i];
#pragma unroll
    for (int i = 0; i < 4; ++i) wsm[bf][wkh * 16 + 8 + i][wc]  = ((const float*)&wr2)[i];
#pragma unroll
    for (int i = 0; i < 4; ++i) wsm[bf][wkh * 16 + 12 + i][wc] = ((const float*)&wr3)[i];
  };

  const int cg = tid >> 4, bg = tid & 15;
  float acc[8][4];
#pragma unroll
  for (int i = 0; i < 8; ++i)
#pragma unroll
    for (int j = 0; j < 4; ++j) acc[i][j] = 0.f;

  load_tile(0);
  store_tile(0);
  __syncthreads();

  for (int kt = 0; kt < 36; ++kt) {
    const int cur = kt & 1;
    if (kt < 35) load_tile(kt + 1);
#pragma unroll 4
    for (int k = 0; k < 32; ++k) {
      const float4 xv  = *(const float4*)&xs[cur][k][bg * 4];
      const float4 wv0 = *(const float4*)&wsm[cur][k][cg * 8];
      const float4 wv1 = *(const float4*)&wsm[cur][k][cg * 8 + 4];
      const float wv[8] = {wv0.x, wv0.y, wv0.z, wv0.w, wv1.x, wv1.y, wv1.z, wv1.w};
      const float xa[4] = {xv.x, xv.y, xv.z, xv.w};
#pragma unroll
      for (int ci = 0; ci < 8; ++ci)
#pragma unroll
        for (int bi = 0; bi < 4; ++bi)
          acc[ci][bi] = fmaf(wv[ci], xa[bi], acc[ci][bi]);
    }
    if (kt < 35) store_tile(cur ^ 1);
    __syncthreads();
  }

  const size_t obase = ((size_t)Tl * G3_ + (size_t)cb * 128) * 64;
#pragma unroll
  for (int ci = 0; ci < 8; ++ci) {
    const int c = cg * 8 + ci;
    const float bv = b_ih[cb * 128 + c];
    float4 o;
    o.x = acc[ci][0] + bv; o.y = acc[ci][1] + bv;
    o.z = acc[ci][2] + bv; o.w = acc[ci][3] + bv;
    *(float4*)&gxC[obase + (size_t)c * 64 + bg * 4] = o;
  }
}

// ---------------------------------------------------------------------------
// Phase 2 (per chunk): MFMA GRU scan v4.
//  * 256 WGs x 256 thr (4 waves). WG g owns 12 gate rows {j,1024+j,2048+j},
//    j in [4g,4g+4), padded to M=16. Wave w = n-tile (b in [16w,16w+16)).
//  * W fragments (bf16 hi+lo) persist in VGPRs for the whole chunk (256 VGPR,
//    1 wave/SIMD via __launch_bounds__(256,1)) -> zero per-step W traffic.
//  * h exchanged via two bf16 planes (hi/lo) in MFMA-FRAGMENT layout
//    [ks][nb][lane][i]: B-operand = one coalesced dwordx4 per ks per plane,
//    loaded with asm sc0/sc1 (L3-fresh), 2-group pipeline, counted vmcnt(8)
//    + sched_barrier(0). Double-buffered planes (A<->B per step).
//  * 3-term split: Whi*hhi + Whi*hlo + Wlo*hhi (error ~2^-17 rel).
//  * A and B both use k = 32*ks + 8*(lane>>4) + i -> any such bijection is
//    correct since hardware pairs A/B by (lane-group, elem).
//  * relaxed single-counter grid barrier (round-4-proven coherence model).
// ---------------------------------------------------------------------------
__global__ __launch_bounds__(256, 1) void scan_kernel(
    const float* __restrict__ gxC, const float* __restrict__ w_hh,
    const float* __restrict__ b_hh,
    char* phiA, char* ploA, char* phiB, char* ploB,
    float* __restrict__ outsC, unsigned* bar, unsigned step0)
{
  const int g = blockIdx.x;
  const int tid = threadIdx.x;
  const int lane = tid & 63;
  const int w = tid >> 6;          // wave id = n-tile index
  const int m = lane & 15;         // A row / D col position
  const int gA = lane >> 4;        // k-group
  const int bl = m;                // gate lane's batch-low (lanes 0-15)

  // ---- A-fragments: rows gate*1024 + 4g + (m&3); zeros for pad rows m>=12
  bf16x8 whi[32], wlo[32];
  {
    const bool valid = (m < 12);
    const int msafe = valid ? m : 0;
    const float* wr = w_hh + (size_t)((msafe >> 2) * 1024 + 4 * g + (msafe & 3)) * 1024;
#pragma unroll
    for (int ks = 0; ks < 32; ++ks) {
      const int kb = ks * 32 + gA * 8;
      float v[8];
      const float4 a0 = *(const float4*)(wr + kb);
      const float4 a1 = *(const float4*)(wr + kb + 4);
      v[0] = a0.x; v[1] = a0.y; v[2] = a0.z; v[3] = a0.w;
      v[4] = a1.x; v[5] = a1.y; v[6] = a1.z; v[7] = a1.w;
#pragma unroll
      for (int i = 0; i < 8; ++i) {
        const float f = valid ? v[i] : 0.f;
        const unsigned short hh = f2bf(f);
        const unsigned short hl = f2bf(f - bf2f(hh));
        whi[ks][i] = (short)hh;
        wlo[ks][i] = (short)hl;
      }
    }
  }

  // ---- gate constants + plane address for this lane's (4 jj, b) slot
  const int ksj = g >> 3;
  const int gf  = (g >> 1) & 3;
  const unsigned gbyte =
      ((unsigned)((ksj * 4 + w) * 64 + gf * 16 + bl)) * 16u + 8u * (g & 1);
  float bh_r[4], bh_z[4], bh_n[4], hold[4];
#pragma unroll
  for (int jj = 0; jj < 4; ++jj) {
    bh_r[jj] = b_hh[4 * g + jj];
    bh_z[jj] = b_hh[1024 + 4 * g + jj];
    bh_n[jj] = b_hh[2048 + 4 * g + jj];
  }
  {
    u32x2 dh, dl;
    GLOAD8(dh, (uint64_t)(uintptr_t)(phiA + gbyte));
    GLOAD8(dl, (uint64_t)(uintptr_t)(ploA + gbyte));
    WAITV(0);
    __builtin_amdgcn_sched_barrier(0);
#pragma unroll
    for (int jj = 0; jj < 4; ++jj) {
      const unsigned short hh = (unsigned short)((dh[jj >> 1] >> ((jj & 1) * 16)) & 0xFFFFu);
      const unsigned short hl = (unsigned short)((dl[jj >> 1] >> ((jj & 1) * 16)) & 0xFFFFu);
      hold[jj] = bf2f(hh) + bf2f(hl);
    }
  }

  char* curHi = phiA; char* curLo = ploA;
  char* nxtHi = phiB; char* nxtLo = ploB;

  for (int s = 0; s < C_; ++s) {
    // ---- gate inputs for this step (plain loads; lanes>=16 replicate bl)
    float gr[4], gz[4], gn[4];
    {
      const float* gp = gxC + (size_t)s * (G3_ * 64) + 16 * w + bl;
#pragma unroll
      for (int jj = 0; jj < 4; ++jj) {
        gr[jj] = gp[(0 * 1024 + 4 * g + jj) * 64];
        gz[jj] = gp[(1 * 1024 + 4 * g + jj) * 64];
        gn[jj] = gp[(2 * 1024 + 4 * g + jj) * 64];
      }
    }

    // ---- MFMA over K: B-frags streamed via asm sc1 loads, 2-group pipeline
    const uint64_t bHi = (uint64_t)(uintptr_t)curHi + (unsigned)((w << 10) + (lane << 4));
    const uint64_t bLo = (uint64_t)(uintptr_t)curLo + (unsigned)((w << 10) + (lane << 4));
    bf16x8 bh[2][4], blo[2][4];
    f32x4 acc[6];
#pragma unroll
    for (int c = 0; c < 6; ++c) acc[c] = (f32x4){0.f, 0.f, 0.f, 0.f};

#pragma unroll
    for (int q = 0; q < 4; ++q) {
      GLOAD16(bh[0][q],  bHi + (unsigned)((0 * 4 + q) * 4096));
      GLOAD16(blo[0][q], bLo + (unsigned)((0 * 4 + q) * 4096));
    }
#pragma unroll
    for (int q = 0; q < 4; ++q) {
      GLOAD16(bh[1][q],  bHi + (unsigned)((1 * 4 + q) * 4096));
      GLOAD16(blo[1][q], bLo + (unsigned)((1 * 4 + q) * 4096));
    }

#pragma unroll
    for (int grp = 0; grp < 8; ++grp) {
      if (grp < 7) { WAITV(8); } else { WAITV(0); }
      __builtin_amdgcn_sched_barrier(0);
      const int buf = grp & 1;
#pragma unroll
      for (int q = 0; q < 4; ++q) {
        const int ks = grp * 4 + q;
        const int p = (ks & 1) * 3;
        acc[p + 0] = __builtin_amdgcn_mfma_f32_16x16x32_bf16(whi[ks], bh[buf][q],  acc[p + 0], 0, 0, 0);
        acc[p + 1] = __builtin_amdgcn_mfma_f32_16x16x32_bf16(whi[ks], blo[buf][q], acc[p + 1], 0, 0, 0);
        acc[p + 2] = __builtin_amdgcn_mfma_f32_16x16x32_bf16(wlo[ks], bh[buf][q],  acc[p + 2], 0, 0, 0);
      }
      if (grp + 2 < 8) {
#pragma unroll
        for (int q = 0; q < 4; ++q) {
          GLOAD16(bh[buf][q],  bHi + (unsigned)(((grp + 2) * 4 + q) * 4096));
          GLOAD16(blo[buf][q], bLo + (unsigned)(((grp + 2) * 4 + q) * 4096));
        }
      }
    }

    f32x4 P = (acc[0] + acc[3]) + (acc[1] + acc[4]) + (acc[2] + acc[5]);

    // ---- gather z/n partials to lanes 0-15 (rows 4..7 live on lanes 16-31,
    //      rows 8..11 on lanes 32-47; reg index = jj; col = lane&15 = b)
    float zs[4], ns[4];
#pragma unroll
    for (int jj = 0; jj < 4; ++jj) {
      zs[jj] = __shfl(P[jj], bl + 16);
      ns[jj] = __shfl(P[jj], bl + 32);
    }

    if (lane < 16) {
      const int b = 16 * w + bl;
      unsigned short hhi[4], hlo[4];
#pragma unroll
      for (int jj = 0; jj < 4; ++jj) {
        const float r = 1.f / (1.f + expf(-(gr[jj] + P[jj] + bh_r[jj])));
        const float z = 1.f / (1.f + expf(-(gz[jj] + zs[jj] + bh_z[jj])));
        const float n = tanhf(gn[jj] + r * (ns[jj] + bh_n[jj]));
        const float hnew = (1.f - z) * n + z * hold[jj];
        hold[jj] = hnew;
        outsC[((size_t)s << 16) + (size_t)((4 * g + jj) << 6) + b] = hnew;
        hhi[jj] = f2bf(hnew);
        hlo[jj] = f2bf(hnew - bf2f(hhi[jj]));
      }
      u32x2 vh, vl;
      vh[0] = (unsigned)hhi[0] | ((unsigned)hhi[1] << 16);
      vh[1] = (unsigned)hhi[2] | ((unsigned)hhi[3] << 16);
      vl[0] = (unsigned)hlo[0] | ((unsigned)hlo[1] << 16);
      vl[1] = (unsigned)hlo[2] | ((unsigned)hlo[3] << 16);
      GSTORE8((uint64_t)(uintptr_t)(nxtHi + gbyte), vh);
      GSTORE8((uint64_t)(uintptr_t)(nxtLo + gbyte), vl);
    }

    // ---- relaxed grid barrier (no cache maintenance; stores drained by
    //      __syncthreads' vmcnt(0) before s_barrier)
    __syncthreads();
    if (tid == 0) {
      asm volatile("s_waitcnt vmcnt(0)" ::: "memory");
      const unsigned tgt = step0 + (unsigned)s + 1u;
      const unsigned old =
          __hip_atomic_fetch_add(bar, 1u, __ATOMIC_RELAXED, __HIP_MEMORY_SCOPE_AGENT);
      if (old == 255u) {
        __hip_atomic_store(bar, 0u, __ATOMIC_RELAXED, __HIP_MEMORY_SCOPE_AGENT);
        asm volatile("s_waitcnt vmcnt(0)" ::: "memory");
        __hip_atomic_store(bar + 544, tgt, __ATOMIC_RELAXED, __HIP_MEMORY_SCOPE_AGENT);
      } else {
        while (__hip_atomic_load(bar + 544, __ATOMIC_RELAXED, __HIP_MEMORY_SCOPE_AGENT) < tgt)
          __builtin_amdgcn_s_sleep(1);
      }
    }
    __syncthreads();

    char* t1 = curHi; curHi = nxtHi; nxtHi = t1;
    char* t2 = curLo; curLo = nxtLo; nxtLo = t2;
  }
}

// ---------------------------------------------------------------------------
// Phase 3 (per chunk): logits + IOBES mask (unchanged)
// ---------------------------------------------------------------------------
__global__ __launch_bounds__(256) void logits_kernel(
    const float* __restrict__ outsC, const int* __restrict__ labels,
    const float* __restrict__ w_out, const float* __restrict__ b_out,
    float* __restrict__ out, int t0)
{
  __shared__ float hs[128 * 64];
  __shared__ float wso[49 * 128];
  const int tl = blockIdx.x;
  const int t  = t0 + tl;
  const int tid = threadIdx.x;
  const int b = tid & 63, lq = tid >> 6;
  const int l0 = lq * 13;
  const int nl = (lq == 3) ? 10 : 13;

  float acc[13];
#pragma unroll
  for (int i = 0; i < 13; ++i) acc[i] = 0.f;

  for (int kc = 0; kc < 8; ++kc) {
    __syncthreads();
#pragma unroll
    for (int i = 0; i < 8; ++i) {
      const int flat = (i << 10) + (tid << 2);
      *(float4*)&hs[flat] = *(const float4*)&outsC[((size_t)tl << 16) + (kc << 13) + flat];
    }
    for (int idx = tid; idx < 1568; idx += 256) {
      const int l = idx >> 5, k4 = idx & 31;
      *(float4*)&wso[l * 128 + (k4 << 2)] =
          *(const float4*)&w_out[(size_t)l * 1024 + (kc << 7) + (k4 << 2)];
    }
    __syncthreads();
    for (int k = 0; k < 128; k += 4) {
      const float h0 = hs[((k + 0) << 6) + b];
      const float h1 = hs[((k + 1) << 6) + b];
      const float h2 = hs[((k + 2) << 6) + b];
      const float h3 = hs[((k + 3) << 6) + b];
#pragma unroll
      for (int li = 0; li < 13; ++li) {
        if (li < nl) {
          const float4 wv = *(const float4*)&wso[(l0 + li) * 128 + k];
          acc[li] = fmaf(wv.w, h3, fmaf(wv.z, h2, fmaf(wv.y, h1, fmaf(wv.x, h0, acc[li]))));
        }
      }
    }
  }

  const int pid = (t > 0) ? labels[b * S_ + t - 1] : 0;
  bool prevOES;
  int ptype = 0;
  if (pid == 0) { prevOES = true; }
  else {
    const int pp = (pid - 1) & 3;   // 0:B 1:I 2:E 3:S
    prevOES = (pp >= 2);
    ptype = (pid - 1) >> 2;
  }
#pragma unroll
  for (int li = 0; li < 13; ++li) {
    if (li < nl) {
      const int l = l0 + li;
      bool ok;
      if (prevOES) {
        ok = (l == 0) || (((l - 1) & 3) == 0) || (((l - 1) & 3) == 3);
      } else {
        ok = (l > 0) && (((l - 1) >> 2) == ptype) &&
             ((((l - 1) & 3) == 1) || (((l - 1) & 3) == 2));
      }
      out[(((size_t)b << 9) + t) * 49 + l] = ok ? (acc[li] + b_out[l]) : -1e12f;
    }
  }
}

// ---------------------------------------------------------------------------
// ws layout (total ~64.6 MB):
//   gxC   @ 0          : 50,331,648 B   [C_][3072][64] f32
//   outsC @ 50,331,648 : 16,777,216 B   [C_][1024][64] f32
//   phiA  @ 67,108,864 :    131,072 B   bf16 h-plane hi, set A
//   ploA  @ 67,239,936 :    131,072 B   bf16 h-plane lo, set A
//   phiB  @ 67,371,008 :    131,072 B
//   ploB  @ 67,502,080 :    131,072 B
//   bar   @ 67,633,152 :      4,096 B   (cnt @ +0, gen @ +544 dwords)
// ---------------------------------------------------------------------------
extern "C" void kernel_launch(void* const* d_in, const int* in_sizes, int n_in,
                              void* d_out, int out_size, void* d_ws, size_t ws_size,
                              hipStream_t stream)
{
  const float* word   = (const float*)d_in[0];
  const int*   labels = (const int*)d_in[1];
  const float* emb    = (const float*)d_in[2];
  const float* w_ih   = (const float*)d_in[3];
  const float* w_hh   = (const float*)d_in[4];
  const float* b_ih   = (const float*)d_in[5];
  const float* b_hh   = (const float*)d_in[6];
  const float* w_out  = (const float*)d_in[7];
  const float* b_out  = (const float*)d_in[8];
  float* out = (float*)d_out;

  char* ws = (char*)d_ws;
  float*    gxC   = (float*)ws;
  float*    outsC = (float*)(ws + 50331648ull);
  char*     phiA  = ws + 67108864ull;
  char*     ploA  = ws + 67239936ull;
  char*     phiB  = ws + 67371008ull;
  char*     ploB  = ws + 67502080ull;
  unsigned* bar   = (unsigned*)(ws + 67633152ull);

  init_kernel<<<dim3(129), dim3(256), 0, stream>>>((float4*)phiA);  // planes+bar=0

  for (int ch = 0; ch < NCH_; ++ch) {
    const int t0 = ch * C_;
    gx_gemm<<<dim3(C_ * 24), dim3(256), 0, stream>>>(word, labels, emb, w_ih, b_ih,
                                                     gxC, t0);
    scan_kernel<<<dim3(256), dim3(256), 0, stream>>>(gxC, w_hh, b_hh,
                                                     phiA, ploA, phiB, ploB,
                                                     outsC, bar, (unsigned)t0);
    logits_kernel<<<dim3(C_), dim3(256), 0, stream>>>(outsC, labels, w_out, b_out,
                                                      out, t0);
  }
}